// Round 8
// baseline (323.024 us; speedup 1.0000x reference)
//
#include <hip/hip_runtime.h>
#include <hip/hip_bf16.h>
#include <stdint.h>

// ---------- types & helpers ----------
using f32x4  = __attribute__((ext_vector_type(4))) float;
using bf16x8 = __attribute__((ext_vector_type(8))) short;
using u16x4  = __attribute__((ext_vector_type(4))) ushort;

#define MFMA16(a, b, c) __builtin_amdgcn_mfma_f32_16x16x32_bf16((a), (b), (c), 0, 0, 0)

__device__ __forceinline__ void gload_lds16(const void* g, void* l) {
    __builtin_amdgcn_global_load_lds(
        (const __attribute__((address_space(1))) void*)g,
        (__attribute__((address_space(3))) void*)l, 16, 0, 0);
}

__device__ __forceinline__ ushort f2bf(float f) {
    union { float f; uint32_t u; } v; v.f = f;
    uint32_t r = v.u + 0x7fffu + ((v.u >> 16) & 1u);
    return (ushort)(r >> 16);
}
__device__ __forceinline__ float bf2f(ushort u) {
    union { uint32_t u; float f; } v; v.u = ((uint32_t)u) << 16;
    return v.f;
}
// hardware packed f32x2 -> bf16x2 (single v_cvt_pk_bf16_f32; T12 recipe)
__device__ __forceinline__ uint32_t pk_bf16(float a, float b) {
    uint32_t r;
    asm("v_cvt_pk_bf16_f32 %0, %1, %2" : "=v"(r) : "v"(a), "v"(b));
    return r;
}
#define EXP2(x) __builtin_amdgcn_exp2f(x)

__device__ __forceinline__ bf16x8 scale8(bf16x8 v, float s) {
    bf16x8 r;
#pragma unroll
    for (int j = 0; j < 8; ++j) r[j] = (short)f2bf(bf2f((ushort)v[j]) * s);
    return r;
}

__device__ __forceinline__ void wgbar() {
    asm volatile("" ::: "memory");
    __builtin_amdgcn_s_barrier();
    asm volatile("" ::: "memory");
}
#define VMW8  asm volatile("s_waitcnt vmcnt(8)" ::: "memory")
#define VMW0  asm volatile("s_waitcnt vmcnt(0)" ::: "memory")
#define LGK0  asm volatile("s_waitcnt lgkmcnt(0)" ::: "memory")
#define PRIO1 __builtin_amdgcn_s_setprio(1)
#define PRIO0 __builtin_amdgcn_s_setprio(0)

#define NEG_BIG (-1.0e30f)

// ---------- pack f32 -> bf16 ----------
__global__ void pack_bf16_k(const float* __restrict__ in, ushort* __restrict__ out, int n4) {
    const int i = blockIdx.x * blockDim.x + threadIdx.x;
    if (i >= n4) return;
    const f32x4 v = *(const f32x4*)(in + (size_t)i * 4);
    u16x4 o;
    o[0] = f2bf(v[0]); o[1] = f2bf(v[1]); o[2] = f2bf(v[2]); o[3] = f2bf(v[3]);
    *(u16x4*)(out + (size_t)i * 4) = o;
}

// ---------- merged weight transpose ----------
__global__ void transpose2_k(const float* __restrict__ wa, ushort* __restrict__ wTa,
                             const float* __restrict__ wp, ushort* __restrict__ wTp) {
    __shared__ ushort tile[32][33];
    const bool isA = blockIdx.x < 96;
    const float* in  = isA ? wa : wp;
    ushort* out      = isA ? wTa : wTp;
    const int C      = isA ? 3072 : 1024;
    const int c0     = (isA ? blockIdx.x : (blockIdx.x - 96)) * 32;
    const int r0     = blockIdx.y * 32;
    const int R      = 1024;
    const int tx = threadIdx.x, ty = threadIdx.y;
    for (int i = ty; i < 32; i += 8)
        tile[i][tx] = f2bf(in[(size_t)(r0 + i) * C + c0 + tx]);
    __syncthreads();
    for (int i = ty; i < 32; i += 8)
        out[(size_t)(c0 + i) * R + r0 + tx] = tile[tx][i];
}

// ---------- 256^2-tile GEMM (unchanged control) ----------
template <int MODE>
__global__ __launch_bounds__(512, 2)
void gemm256(const ushort* __restrict__ A, const ushort* __restrict__ BT,
             const float* __restrict__ bias, float* __restrict__ outF,
             ushort* __restrict__ qk, ushort* __restrict__ vt,
             int N, int K) {
    __shared__ __align__(16) ushort As[2][256 * 64];
    __shared__ __align__(16) ushort Bs[2][256 * 64];
    const int tid  = threadIdx.x;
    const int lane = tid & 63;
    const int wid  = tid >> 6;
    const int l15  = lane & 15, lg = lane >> 4;
    const int wm = (wid >> 2) * 128;
    const int wn = (wid & 3) * 64;

    const int cpx = gridDim.x >> 3;
    const int swz = (blockIdx.x & 7) * cpx + (blockIdx.x >> 3);
    const int tile_m = (swz & 31) << 8;
    const int tile_n = (swz >> 5) << 8;

    const f32x4 fzero = {0.f, 0.f, 0.f, 0.f};
    f32x4 acc[8][4];
#pragma unroll
    for (int i = 0; i < 8; ++i)
#pragma unroll
        for (int j = 0; j < 4; ++j) acc[i][j] = fzero;

    const int srow = tid >> 3;
    const int sch  = (tid & 7) ^ (srow & 7);
    const ushort* aP0 = A  + (size_t)(tile_m + srow) * K + sch * 8;
    const ushort* bP0 = BT + (size_t)(tile_n + srow) * K + sch * 8;
    const int d0 = tid * 16;

    auto STA = [&](int buf, int kt) {
#pragma unroll
        for (int i = 0; i < 4; ++i)
            gload_lds16(aP0 + (size_t)i * 64 * K + kt * 64, (char*)As[buf] + d0 + i * 8192);
    };
    auto STB = [&](int buf, int kt) {
#pragma unroll
        for (int i = 0; i < 4; ++i)
            gload_lds16(bP0 + (size_t)i * 64 * K + kt * 64, (char*)Bs[buf] + d0 + i * 8192);
    };
    auto LDA = [&](const char* Ab, int mh, bf16x8* ar) {
#pragma unroll
        for (int mf = 0; mf < 4; ++mf) {
            const int row = wm + (mh * 4 + mf) * 16 + l15;
#pragma unroll
            for (int kk = 0; kk < 2; ++kk)
                ar[mf * 2 + kk] = *(const bf16x8*)(Ab + row * 128 + ((((kk << 2) + lg) ^ (row & 7)) << 4));
        }
    };
    auto LDB = [&](const char* Bb, int nh, bf16x8* br) {
#pragma unroll
        for (int nf = 0; nf < 2; ++nf) {
            const int row = wn + (nh * 2 + nf) * 16 + l15;
#pragma unroll
            for (int kk = 0; kk < 2; ++kk)
                br[nf * 2 + kk] = *(const bf16x8*)(Bb + row * 128 + ((((kk << 2) + lg) ^ (row & 7)) << 4));
        }
    };
    auto MM = [&](const bf16x8* ar, const bf16x8* br, int mh, int nh) {
#pragma unroll
        for (int mf = 0; mf < 4; ++mf)
#pragma unroll
            for (int nf = 0; nf < 2; ++nf)
#pragma unroll
                for (int kk = 0; kk < 2; ++kk)
                    acc[mh * 4 + mf][nh * 2 + nf] =
                        MFMA16(ar[mf * 2 + kk], br[nf * 2 + kk], acc[mh * 4 + mf][nh * 2 + nf]);
    };

    const int nt = K >> 6;
    STA(0, 0); STB(0, 0);
    STA(1, 1); STB(1, 1);
    int cur = 0;
    for (int t = 0; t < nt; ++t) {
        const char* Ab = (const char*)As[cur];
        const char* Bb = (const char*)Bs[cur];
        const bool pre = (t + 2 < nt);
        if (t < nt - 1) { VMW8; } else { VMW0; }
        wgbar();
        bf16x8 ar[8], br01[4], br23[4];
        LDA(Ab, 0, ar); LDB(Bb, 0, br01);
        wgbar(); LGK0;
        PRIO1; MM(ar, br01, 0, 0); PRIO0;
        wgbar();
        LDB(Bb, 1, br23);
        wgbar(); LGK0;
        PRIO1; MM(ar, br23, 0, 1); PRIO0;
        wgbar();
        LDA(Ab, 1, ar);
        if (pre) STB(cur, t + 2);
        wgbar(); LGK0;
        PRIO1; MM(ar, br23, 1, 1); PRIO0;
        wgbar();
        if (pre) STA(cur, t + 2);
        __builtin_amdgcn_sched_barrier(0);
        PRIO1; MM(ar, br01, 1, 0); PRIO0;
        cur ^= 1;
    }

#pragma unroll
    for (int nf = 0; nf < 4; ++nf) {
        const int col = tile_n + wn + nf * 16 + l15;
        const float bv = bias[col];
#pragma unroll
        for (int mf = 0; mf < 8; ++mf) {
            const int row = tile_m + wm + mf * 16 + lg * 4;
            float v0 = acc[mf][nf][0] + bv, v1 = acc[mf][nf][1] + bv;
            float v2 = acc[mf][nf][2] + bv, v3 = acc[mf][nf][3] + bv;
            if (MODE == 0) {
                outF[(size_t)(row + 0) * N + col] = v0;
                outF[(size_t)(row + 1) * N + col] = v1;
                outF[(size_t)(row + 2) * N + col] = v2;
                outF[(size_t)(row + 3) * N + col] = v3;
            } else {
                if (col < 2048) {
                    qk[(size_t)(row + 0) * 2048 + col] = f2bf(v0);
                    qk[(size_t)(row + 1) * 2048 + col] = f2bf(v1);
                    qk[(size_t)(row + 2) * 2048 + col] = f2bf(v2);
                    qk[(size_t)(row + 3) * 2048 + col] = f2bf(v3);
                } else {
                    const int vc = col - 2048;
                    const int bb = row >> 11, tt = row & 2047;
                    uint2 w; w.x = pk_bf16(v0, v1); w.y = pk_bf16(v2, v3);
                    *(uint2*)(vt + ((size_t)(bb * 16 + (vc >> 6)) * 64 + (vc & 63)) * 2048 + tt) = w;
                }
            }
        }
    }
}

// ---------- causal flash attention: fixed-max, native exp2, 1 q-tile/block ----------
// grid (16, 64): block bx handles q-tile qt = 15-bx (descending cost for packing).
// 1024 blocks -> 3 blocks/CU resident (48KB LDS) = 12 waves/CU.
__global__ __launch_bounds__(256)
void attn_fwd(const ushort* __restrict__ qk, const ushort* __restrict__ vt,
              ushort* __restrict__ ao) {
    const int tid  = threadIdx.x;
    const int lane = tid & 63;
    const int w    = tid >> 6;
    const int l15  = lane & 15, lg = lane >> 4;
    const int bh = blockIdx.y;
    const int b = bh >> 4, h = bh & 15;

    __shared__ __align__(16) ushort Ks[2][64 * 64];   // [kv][d] rows 128B, chunk^(row&7)
    __shared__ __align__(16) ushort Vs[2][64 * 64];   // [d][kv] rows 128B, chunk^(row&7)
    __shared__ __align__(16) ushort Ps[4][32 * 64];   // per-wave P [32 q][64 kv], XOR-swizzled

    char* psw = (char*)&Ps[w][0];
    const int pswz = (l15 & 7) << 4;

    const ushort* kbase = qk + (size_t)b * 2048 * 2048 + 1024 + h * 64;
    const ushort* vbase = vt + (size_t)bh * 64 * 2048;
    const float sscale = 0.125f * 1.4426950408889634f;

    const int srow0 = tid >> 3,         schk0 = (tid & 7) ^ (srow0 & 7);
    const int srow1 = (256 + tid) >> 3, schk1 = (tid & 7) ^ (srow1 & 7);

    const int qt = 15 - blockIdx.x;               // big tiles first
    const int q0 = qt * 128;
    const int qw = q0 + w * 32;

    const ushort* qrow = qk + ((size_t)(b * 2048 + qw + l15)) * 2048 + h * 64 + lg * 8;
    bf16x8 qf[2][2];
    qf[0][0] = scale8(*(const bf16x8*)(qrow), sscale);
    qf[0][1] = scale8(*(const bf16x8*)(qrow + 32), sscale);
    qf[1][0] = scale8(*(const bf16x8*)(qrow + 16 * 2048), sscale);
    qf[1][1] = scale8(*(const bf16x8*)(qrow + 16 * 2048 + 32), sscale);

    const f32x4 fzero = {0.f, 0.f, 0.f, 0.f};
    f32x4 o[2][4];
#pragma unroll
    for (int qh = 0; qh < 2; ++qh)
#pragma unroll
        for (int f = 0; f < 4; ++f) o[qh][f] = fzero;
    float lrun[2] = {0.f, 0.f};

    const int nt = q0 / 64 + 2;

    {
        gload_lds16(kbase + (size_t)srow0 * 2048 + schk0 * 8, (char*)Ks[0] + tid * 16);
        gload_lds16(kbase + (size_t)srow1 * 2048 + schk1 * 8, (char*)Ks[0] + (256 + tid) * 16);
        gload_lds16(vbase + (size_t)srow0 * 2048 + schk0 * 8, (char*)Vs[0] + tid * 16);
        gload_lds16(vbase + (size_t)srow1 * 2048 + schk1 * 8, (char*)Vs[0] + (256 + tid) * 16);
    }
    __syncthreads();

    for (int t = 0; t < nt; ++t) {
        const int cur = t & 1;
        const int kv0 = t * 64;
        if (t + 1 < nt) {
            const int nkv = kv0 + 64;
            ushort* kd = Ks[cur ^ 1];
            ushort* vd = Vs[cur ^ 1];
            gload_lds16(kbase + (size_t)(nkv + srow0) * 2048 + schk0 * 8, (char*)kd + tid * 16);
            gload_lds16(kbase + (size_t)(nkv + srow1) * 2048 + schk1 * 8, (char*)kd + (256 + tid) * 16);
            gload_lds16(vbase + (size_t)srow0 * 2048 + nkv + schk0 * 8, (char*)vd + tid * 16);
            gload_lds16(vbase + (size_t)srow1 * 2048 + nkv + schk1 * 8, (char*)vd + (256 + tid) * 16);
        }

        if (kv0 <= qw + 31) {
            const char* kls = (const char*)Ks[cur];
            const char* vls = (const char*)Vs[cur];

            bf16x8 kf[4][2];
#pragma unroll
            for (int hh = 0; hh < 4; ++hh)
#pragma unroll
                for (int dc = 0; dc < 2; ++dc)
                    kf[hh][dc] = *(const bf16x8*)(kls + (hh * 16 + l15) * 128 +
                                                  (((dc * 4 + lg) ^ (l15 & 7)) << 4));

#pragma unroll
            for (int qh = 0; qh < 2; ++qh) {
                if (kv0 > qw + qh * 16 + 15) continue;
                f32x4 st[4] = {fzero, fzero, fzero, fzero};
#pragma unroll
                for (int hh = 0; hh < 4; ++hh)
#pragma unroll
                    for (int dc = 0; dc < 2; ++dc)
                        st[hh] = MFMA16(kf[hh][dc], qf[qh][dc], st[hh]);

                float p[16];
#pragma unroll
                for (int hh = 0; hh < 4; ++hh)
#pragma unroll
                    for (int i = 0; i < 4; ++i) p[hh * 4 + i] = st[hh][i];
                if (kv0 + 63 > qw + qh * 16) {
                    const int qg = qw + qh * 16 + l15;
#pragma unroll
                    for (int hh = 0; hh < 4; ++hh)
#pragma unroll
                        for (int i = 0; i < 4; ++i) {
                            const int kvg = kv0 + hh * 16 + lg * 4 + i;
                            if (kvg > qg) p[hh * 4 + i] = NEG_BIG;
                        }
                }

                // fixed-max softmax: p = exp2(s) (native v_exp_f32); row-sum across lg
                float rs = 0.f;
#pragma unroll
                for (int j = 0; j < 16; ++j) { p[j] = EXP2(p[j]); rs += p[j]; }
                rs += __shfl_xor(rs, 16);
                rs += __shfl_xor(rs, 32);
                lrun[qh] += rs;

                const int prow = qh * 16 + l15;
#pragma unroll
                for (int hh = 0; hh < 4; ++hh) {
                    uint2 pk;
                    pk.x = pk_bf16(p[hh * 4 + 0], p[hh * 4 + 1]);
                    pk.y = pk_bf16(p[hh * 4 + 2], p[hh * 4 + 3]);
                    *(uint2*)(psw + ((prow * 128 + hh * 32 + lg * 8) ^ pswz)) = pk;
                }
            }

            bf16x8 pf[2][2];
#pragma unroll
            for (int qh = 0; qh < 2; ++qh)
#pragma unroll
                for (int ks = 0; ks < 2; ++ks)
                    pf[qh][ks] = *(const bf16x8*)(psw + (((qh * 16 + l15) * 128 + ks * 64 + lg * 16) ^ pswz));

#pragma unroll
            for (int f = 0; f < 4; ++f) {
                const int vrow = f * 16 + l15;
                bf16x8 vf0 = *(const bf16x8*)(vls + vrow * 128 + ((lg ^ (l15 & 7)) << 4));
                bf16x8 vf1 = *(const bf16x8*)(vls + vrow * 128 + (((4 + lg) ^ (l15 & 7)) << 4));
#pragma unroll
                for (int qh = 0; qh < 2; ++qh) {
                    if (kv0 > qw + qh * 16 + 15) continue;
                    o[qh][f] = MFMA16(pf[qh][0], vf0, o[qh][f]);
                    o[qh][f] = MFMA16(pf[qh][1], vf1, o[qh][f]);
                }
            }
        }
        __syncthreads();
    }

#pragma unroll
    for (int qh = 0; qh < 2; ++qh) {
        float lr[4];
#pragma unroll
        for (int i = 0; i < 4; ++i) lr[i] = __shfl(lrun[qh], lg * 4 + i);
#pragma unroll
        for (int f = 0; f < 4; ++f)
#pragma unroll
            for (int i = 0; i < 4; ++i) {
                const int row = qw + qh * 16 + lg * 4 + i;
                const int col = h * 64 + f * 16 + l15;
                ao[((size_t)(b * 2048 + row)) * 1024 + col] = f2bf(o[qh][f][i] / lr[i]);
            }
    }
}

// ---------- launch ----------
extern "C" void kernel_launch(void* const* d_in, const int* in_sizes, int n_in,
                              void* d_out, int out_size, void* d_ws, size_t ws_size,
                              hipStream_t stream) {
    const float* x      = (const float*)d_in[0];
    const float* w_attn = (const float*)d_in[1];
    const float* b_attn = (const float*)d_in[2];
    const float* w_proj = (const float*)d_in[3];
    const float* b_proj = (const float*)d_in[4];
    float* out = (float*)d_out;

    ushort* ws  = (ushort*)d_ws;
    ushort* xb  = ws;                                   // 8192*1024
    ushort* wTa = xb  + (size_t)8192 * 1024;            // 3072*1024
    ushort* wTp = wTa + (size_t)3072 * 1024;            // 1024*1024
    ushort* qkb = wTp + (size_t)1024 * 1024;            // 8192*2048
    ushort* vtb = qkb + (size_t)8192 * 2048;            // 64*64*2048
    ushort* aob = vtb + (size_t)64 * 64 * 2048;         // 8192*1024
    const size_t needed = ((size_t)8192 * 1024 + (size_t)3072 * 1024 + (size_t)1024 * 1024 +
                           (size_t)8192 * 2048 + (size_t)64 * 64 * 2048 + (size_t)8192 * 1024) * 2;
    if (ws_size < needed) return;

    pack_bf16_k<<<8192, 256, 0, stream>>>(x, xb, 8192 * 1024 / 4);
    transpose2_k<<<dim3(128, 32), dim3(32, 8), 0, stream>>>(w_attn, wTa, w_proj, wTp);
    gemm256<1><<<384, 512, 0, stream>>>(xb, wTa, b_attn, nullptr, qkb, vtb, 3072, 1024);
    attn_fwd<<<dim3(16, 64), 256, 0, stream>>>(qkb, vtb, aob);
    gemm256<0><<<128, 512, 0, stream>>>(aob, wTp, b_proj, out, nullptr, nullptr, 1024, 1024);
}

// Round 9
// 286.203 us; speedup vs baseline: 1.1287x; 1.1287x over previous
//
#include <hip/hip_runtime.h>
#include <hip/hip_bf16.h>
#include <stdint.h>

// ---------- types & helpers ----------
using f32x4  = __attribute__((ext_vector_type(4))) float;
using bf16x8 = __attribute__((ext_vector_type(8))) short;
using u16x4  = __attribute__((ext_vector_type(4))) ushort;

#define MFMA16(a, b, c) __builtin_amdgcn_mfma_f32_16x16x32_bf16((a), (b), (c), 0, 0, 0)

__device__ __forceinline__ void gload_lds16(const void* g, void* l) {
    __builtin_amdgcn_global_load_lds(
        (const __attribute__((address_space(1))) void*)g,
        (__attribute__((address_space(3))) void*)l, 16, 0, 0);
}

__device__ __forceinline__ ushort f2bf(float f) {
    union { float f; uint32_t u; } v; v.f = f;
    uint32_t r = v.u + 0x7fffu + ((v.u >> 16) & 1u);
    return (ushort)(r >> 16);
}
__device__ __forceinline__ float bf2f(ushort u) {
    union { uint32_t u; float f; } v; v.u = ((uint32_t)u) << 16;
    return v.f;
}
// hardware packed f32x2 -> bf16x2 (single v_cvt_pk_bf16_f32)
__device__ __forceinline__ uint32_t pk_bf16(float a, float b) {
    uint32_t r;
    asm("v_cvt_pk_bf16_f32 %0, %1, %2" : "=v"(r) : "v"(a), "v"(b));
    return r;
}
#define EXP2(x) __builtin_amdgcn_exp2f(x)

__device__ __forceinline__ bf16x8 scale8(bf16x8 v, float s) {
    bf16x8 r;
#pragma unroll
    for (int j = 0; j < 8; ++j) r[j] = (short)f2bf(bf2f((ushort)v[j]) * s);
    return r;
}

__device__ __forceinline__ void wgbar() {
    asm volatile("" ::: "memory");
    __builtin_amdgcn_s_barrier();
    asm volatile("" ::: "memory");
}
#define VMW8  asm volatile("s_waitcnt vmcnt(8)" ::: "memory")
#define VMW0  asm volatile("s_waitcnt vmcnt(0)" ::: "memory")
#define LGK0  asm volatile("s_waitcnt lgkmcnt(0)" ::: "memory")
#define PRIO1 __builtin_amdgcn_s_setprio(1)
#define PRIO0 __builtin_amdgcn_s_setprio(0)

#define NEG_BIG (-1.0e30f)

// ---------- pack f32 -> bf16 ----------
__global__ void pack_bf16_k(const float* __restrict__ in, ushort* __restrict__ out, int n4) {
    const int i = blockIdx.x * blockDim.x + threadIdx.x;
    if (i >= n4) return;
    const f32x4 v = *(const f32x4*)(in + (size_t)i * 4);
    u16x4 o;
    o[0] = f2bf(v[0]); o[1] = f2bf(v[1]); o[2] = f2bf(v[2]); o[3] = f2bf(v[3]);
    *(u16x4*)(out + (size_t)i * 4) = o;
}

// ---------- merged weight transpose ----------
__global__ void transpose2_k(const float* __restrict__ wa, ushort* __restrict__ wTa,
                             const float* __restrict__ wp, ushort* __restrict__ wTp) {
    __shared__ ushort tile[32][33];
    const bool isA = blockIdx.x < 96;
    const float* in  = isA ? wa : wp;
    ushort* out      = isA ? wTa : wTp;
    const int C      = isA ? 3072 : 1024;
    const int c0     = (isA ? blockIdx.x : (blockIdx.x - 96)) * 32;
    const int r0     = blockIdx.y * 32;
    const int R      = 1024;
    const int tx = threadIdx.x, ty = threadIdx.y;
    for (int i = ty; i < 32; i += 8)
        tile[i][tx] = f2bf(in[(size_t)(r0 + i) * C + c0 + tx]);
    __syncthreads();
    for (int i = ty; i < 32; i += 8)
        out[(size_t)(c0 + i) * R + r0 + tx] = tile[tx][i];
}

// ---------- 256^2-tile GEMM (unchanged control) ----------
template <int MODE>
__global__ __launch_bounds__(512, 2)
void gemm256(const ushort* __restrict__ A, const ushort* __restrict__ BT,
             const float* __restrict__ bias, float* __restrict__ outF,
             ushort* __restrict__ qk, ushort* __restrict__ vt,
             int N, int K) {
    __shared__ __align__(16) ushort As[2][256 * 64];
    __shared__ __align__(16) ushort Bs[2][256 * 64];
    const int tid  = threadIdx.x;
    const int lane = tid & 63;
    const int wid  = tid >> 6;
    const int l15  = lane & 15, lg = lane >> 4;
    const int wm = (wid >> 2) * 128;
    const int wn = (wid & 3) * 64;

    const int cpx = gridDim.x >> 3;
    const int swz = (blockIdx.x & 7) * cpx + (blockIdx.x >> 3);
    const int tile_m = (swz & 31) << 8;
    const int tile_n = (swz >> 5) << 8;

    const f32x4 fzero = {0.f, 0.f, 0.f, 0.f};
    f32x4 acc[8][4];
#pragma unroll
    for (int i = 0; i < 8; ++i)
#pragma unroll
        for (int j = 0; j < 4; ++j) acc[i][j] = fzero;

    const int srow = tid >> 3;
    const int sch  = (tid & 7) ^ (srow & 7);
    const ushort* aP0 = A  + (size_t)(tile_m + srow) * K + sch * 8;
    const ushort* bP0 = BT + (size_t)(tile_n + srow) * K + sch * 8;
    const int d0 = tid * 16;

    auto STA = [&](int buf, int kt) {
#pragma unroll
        for (int i = 0; i < 4; ++i)
            gload_lds16(aP0 + (size_t)i * 64 * K + kt * 64, (char*)As[buf] + d0 + i * 8192);
    };
    auto STB = [&](int buf, int kt) {
#pragma unroll
        for (int i = 0; i < 4; ++i)
            gload_lds16(bP0 + (size_t)i * 64 * K + kt * 64, (char*)Bs[buf] + d0 + i * 8192);
    };
    auto LDA = [&](const char* Ab, int mh, bf16x8* ar) {
#pragma unroll
        for (int mf = 0; mf < 4; ++mf) {
            const int row = wm + (mh * 4 + mf) * 16 + l15;
#pragma unroll
            for (int kk = 0; kk < 2; ++kk)
                ar[mf * 2 + kk] = *(const bf16x8*)(Ab + row * 128 + ((((kk << 2) + lg) ^ (row & 7)) << 4));
        }
    };
    auto LDB = [&](const char* Bb, int nh, bf16x8* br) {
#pragma unroll
        for (int nf = 0; nf < 2; ++nf) {
            const int row = wn + (nh * 2 + nf) * 16 + l15;
#pragma unroll
            for (int kk = 0; kk < 2; ++kk)
                br[nf * 2 + kk] = *(const bf16x8*)(Bb + row * 128 + ((((kk << 2) + lg) ^ (row & 7)) << 4));
        }
    };
    auto MM = [&](const bf16x8* ar, const bf16x8* br, int mh, int nh) {
#pragma unroll
        for (int mf = 0; mf < 4; ++mf)
#pragma unroll
            for (int nf = 0; nf < 2; ++nf)
#pragma unroll
                for (int kk = 0; kk < 2; ++kk)
                    acc[mh * 4 + mf][nh * 2 + nf] =
                        MFMA16(ar[mf * 2 + kk], br[nf * 2 + kk], acc[mh * 4 + mf][nh * 2 + nf]);
    };

    const int nt = K >> 6;
    STA(0, 0); STB(0, 0);
    STA(1, 1); STB(1, 1);
    int cur = 0;
    for (int t = 0; t < nt; ++t) {
        const char* Ab = (const char*)As[cur];
        const char* Bb = (const char*)Bs[cur];
        const bool pre = (t + 2 < nt);
        if (t < nt - 1) { VMW8; } else { VMW0; }
        wgbar();
        bf16x8 ar[8], br01[4], br23[4];
        LDA(Ab, 0, ar); LDB(Bb, 0, br01);
        wgbar(); LGK0;
        PRIO1; MM(ar, br01, 0, 0); PRIO0;
        wgbar();
        LDB(Bb, 1, br23);
        wgbar(); LGK0;
        PRIO1; MM(ar, br23, 0, 1); PRIO0;
        wgbar();
        LDA(Ab, 1, ar);
        if (pre) STB(cur, t + 2);
        wgbar(); LGK0;
        PRIO1; MM(ar, br23, 1, 1); PRIO0;
        wgbar();
        if (pre) STA(cur, t + 2);
        __builtin_amdgcn_sched_barrier(0);
        PRIO1; MM(ar, br01, 1, 0); PRIO0;
        cur ^= 1;
    }

#pragma unroll
    for (int nf = 0; nf < 4; ++nf) {
        const int col = tile_n + wn + nf * 16 + l15;
        const float bv = bias[col];
#pragma unroll
        for (int mf = 0; mf < 8; ++mf) {
            const int row = tile_m + wm + mf * 16 + lg * 4;
            float v0 = acc[mf][nf][0] + bv, v1 = acc[mf][nf][1] + bv;
            float v2 = acc[mf][nf][2] + bv, v3 = acc[mf][nf][3] + bv;
            if (MODE == 0) {
                outF[(size_t)(row + 0) * N + col] = v0;
                outF[(size_t)(row + 1) * N + col] = v1;
                outF[(size_t)(row + 2) * N + col] = v2;
                outF[(size_t)(row + 3) * N + col] = v3;
            } else {
                if (col < 2048) {
                    qk[(size_t)(row + 0) * 2048 + col] = f2bf(v0);
                    qk[(size_t)(row + 1) * 2048 + col] = f2bf(v1);
                    qk[(size_t)(row + 2) * 2048 + col] = f2bf(v2);
                    qk[(size_t)(row + 3) * 2048 + col] = f2bf(v3);
                } else {
                    const int vc = col - 2048;
                    const int bb = row >> 11, tt = row & 2047;
                    uint2 w; w.x = pk_bf16(v0, v1); w.y = pk_bf16(v2, v3);
                    *(uint2*)(vt + ((size_t)(bb * 16 + (vc >> 6)) * 64 + (vc & 63)) * 2048 + tt) = w;
                }
            }
        }
    }
}

// ---------- causal flash attention: fold-paired + fixed-max + native VALU ops ----------
// grid (8, 64), block 256 = 4 waves x 32 q-rows. Block bx handles q-tiles
// {bx, 15-bx}: uniform 34 kv-iterations. Fixed-max softmax (m=0), native exp2,
// hw cvt_pk for P pack. 48KB LDS.
__global__ __launch_bounds__(256)
void attn_fwd(const ushort* __restrict__ qk, const ushort* __restrict__ vt,
              ushort* __restrict__ ao) {
    const int tid  = threadIdx.x;
    const int lane = tid & 63;
    const int w    = tid >> 6;
    const int l15  = lane & 15, lg = lane >> 4;
    const int bh = blockIdx.y;
    const int b = bh >> 4, h = bh & 15;

    __shared__ __align__(16) ushort Ks[2][64 * 64];   // [kv][d] rows 128B, chunk^(row&7)
    __shared__ __align__(16) ushort Vs[2][64 * 64];   // [d][kv] rows 128B, chunk^(row&7)
    __shared__ __align__(16) ushort Ps[4][32 * 64];   // per-wave P, XOR-swizzled

    char* psw = (char*)&Ps[w][0];
    const int pswz = (l15 & 7) << 4;

    const ushort* kbase = qk + (size_t)b * 2048 * 2048 + 1024 + h * 64;
    const ushort* vbase = vt + (size_t)bh * 64 * 2048;
    const float sscale = 0.125f * 1.4426950408889634f;

    const int srow0 = tid >> 3,         schk0 = (tid & 7) ^ (srow0 & 7);
    const int srow1 = (256 + tid) >> 3, schk1 = (tid & 7) ^ (srow1 & 7);

    for (int pass = 0; pass < 2; ++pass) {
        const int q0 = (pass ? (15 - blockIdx.x) : blockIdx.x) * 128;
        const int qw = q0 + w * 32;

        const ushort* qrow = qk + ((size_t)(b * 2048 + qw + l15)) * 2048 + h * 64 + lg * 8;
        bf16x8 qf[2][2];
        qf[0][0] = scale8(*(const bf16x8*)(qrow), sscale);
        qf[0][1] = scale8(*(const bf16x8*)(qrow + 32), sscale);
        qf[1][0] = scale8(*(const bf16x8*)(qrow + 16 * 2048), sscale);
        qf[1][1] = scale8(*(const bf16x8*)(qrow + 16 * 2048 + 32), sscale);

        const f32x4 fzero = {0.f, 0.f, 0.f, 0.f};
        f32x4 o[2][4];
#pragma unroll
        for (int qh = 0; qh < 2; ++qh)
#pragma unroll
            for (int f = 0; f < 4; ++f) o[qh][f] = fzero;
        float lrun[2] = {0.f, 0.f};

        const int nt = q0 / 64 + 2;

        {
            gload_lds16(kbase + (size_t)srow0 * 2048 + schk0 * 8, (char*)Ks[0] + tid * 16);
            gload_lds16(kbase + (size_t)srow1 * 2048 + schk1 * 8, (char*)Ks[0] + (256 + tid) * 16);
            gload_lds16(vbase + (size_t)srow0 * 2048 + schk0 * 8, (char*)Vs[0] + tid * 16);
            gload_lds16(vbase + (size_t)srow1 * 2048 + schk1 * 8, (char*)Vs[0] + (256 + tid) * 16);
        }
        __syncthreads();

        for (int t = 0; t < nt; ++t) {
            const int cur = t & 1;
            const int kv0 = t * 64;
            if (t + 1 < nt) {
                const int nkv = kv0 + 64;
                ushort* kd = Ks[cur ^ 1];
                ushort* vd = Vs[cur ^ 1];
                gload_lds16(kbase + (size_t)(nkv + srow0) * 2048 + schk0 * 8, (char*)kd + tid * 16);
                gload_lds16(kbase + (size_t)(nkv + srow1) * 2048 + schk1 * 8, (char*)kd + (256 + tid) * 16);
                gload_lds16(vbase + (size_t)srow0 * 2048 + nkv + schk0 * 8, (char*)vd + tid * 16);
                gload_lds16(vbase + (size_t)srow1 * 2048 + nkv + schk1 * 8, (char*)vd + (256 + tid) * 16);
            }

            if (kv0 <= qw + 31) {
                const char* kls = (const char*)Ks[cur];
                const char* vls = (const char*)Vs[cur];

                bf16x8 kf[4][2];
#pragma unroll
                for (int hh = 0; hh < 4; ++hh)
#pragma unroll
                    for (int dc = 0; dc < 2; ++dc)
                        kf[hh][dc] = *(const bf16x8*)(kls + (hh * 16 + l15) * 128 +
                                                      (((dc * 4 + lg) ^ (l15 & 7)) << 4));

#pragma unroll
                for (int qh = 0; qh < 2; ++qh) {
                    if (kv0 > qw + qh * 16 + 15) continue;
                    f32x4 st[4] = {fzero, fzero, fzero, fzero};
#pragma unroll
                    for (int hh = 0; hh < 4; ++hh)
#pragma unroll
                        for (int dc = 0; dc < 2; ++dc)
                            st[hh] = MFMA16(kf[hh][dc], qf[qh][dc], st[hh]);

                    float p[16];
#pragma unroll
                    for (int hh = 0; hh < 4; ++hh)
#pragma unroll
                        for (int i = 0; i < 4; ++i) p[hh * 4 + i] = st[hh][i];
                    if (kv0 + 63 > qw + qh * 16) {
                        const int qg = qw + qh * 16 + l15;
#pragma unroll
                        for (int hh = 0; hh < 4; ++hh)
#pragma unroll
                            for (int i = 0; i < 4; ++i) {
                                const int kvg = kv0 + hh * 16 + lg * 4 + i;
                                if (kvg > qg) p[hh * 4 + i] = NEG_BIG;
                            }
                    }

                    // fixed-max softmax: p = exp2(s) (native v_exp_f32)
                    float rs = 0.f;
#pragma unroll
                    for (int j = 0; j < 16; ++j) { p[j] = EXP2(p[j]); rs += p[j]; }
                    rs += __shfl_xor(rs, 16);
                    rs += __shfl_xor(rs, 32);
                    lrun[qh] += rs;

                    const int prow = qh * 16 + l15;
#pragma unroll
                    for (int hh = 0; hh < 4; ++hh) {
                        uint2 pk;
                        pk.x = pk_bf16(p[hh * 4 + 0], p[hh * 4 + 1]);
                        pk.y = pk_bf16(p[hh * 4 + 2], p[hh * 4 + 3]);
                        *(uint2*)(psw + ((prow * 128 + hh * 32 + lg * 8) ^ pswz)) = pk;
                    }
                }

                bf16x8 pf[2][2];
#pragma unroll
                for (int qh = 0; qh < 2; ++qh)
#pragma unroll
                    for (int ks = 0; ks < 2; ++ks)
                        pf[qh][ks] = *(const bf16x8*)(psw + (((qh * 16 + l15) * 128 + ks * 64 + lg * 16) ^ pswz));

#pragma unroll
                for (int f = 0; f < 4; ++f) {
                    const int vrow = f * 16 + l15;
                    bf16x8 vf0 = *(const bf16x8*)(vls + vrow * 128 + ((lg ^ (l15 & 7)) << 4));
                    bf16x8 vf1 = *(const bf16x8*)(vls + vrow * 128 + (((4 + lg) ^ (l15 & 7)) << 4));
#pragma unroll
                    for (int qh = 0; qh < 2; ++qh) {
                        if (kv0 > qw + qh * 16 + 15) continue;
                        o[qh][f] = MFMA16(pf[qh][0], vf0, o[qh][f]);
                        o[qh][f] = MFMA16(pf[qh][1], vf1, o[qh][f]);
                    }
                }
            }
            __syncthreads();
        }

#pragma unroll
        for (int qh = 0; qh < 2; ++qh) {
            float lr[4];
#pragma unroll
            for (int i = 0; i < 4; ++i) lr[i] = __shfl(lrun[qh], lg * 4 + i);
#pragma unroll
            for (int f = 0; f < 4; ++f)
#pragma unroll
                for (int i = 0; i < 4; ++i) {
                    const int row = qw + qh * 16 + lg * 4 + i;
                    const int col = h * 64 + f * 16 + l15;
                    ao[((size_t)(b * 2048 + row)) * 1024 + col] = f2bf(o[qh][f][i] / lr[i]);
                }
        }
    }
}

// ---------- launch ----------
extern "C" void kernel_launch(void* const* d_in, const int* in_sizes, int n_in,
                              void* d_out, int out_size, void* d_ws, size_t ws_size,
                              hipStream_t stream) {
    const float* x      = (const float*)d_in[0];
    const float* w_attn = (const float*)d_in[1];
    const float* b_attn = (const float*)d_in[2];
    const float* w_proj = (const float*)d_in[3];
    const float* b_proj = (const float*)d_in[4];
    float* out = (float*)d_out;

    ushort* ws  = (ushort*)d_ws;
    ushort* xb  = ws;                                   // 8192*1024
    ushort* wTa = xb  + (size_t)8192 * 1024;            // 3072*1024
    ushort* wTp = wTa + (size_t)3072 * 1024;            // 1024*1024
    ushort* qkb = wTp + (size_t)1024 * 1024;            // 8192*2048
    ushort* vtb = qkb + (size_t)8192 * 2048;            // 64*64*2048
    ushort* aob = vtb + (size_t)64 * 64 * 2048;         // 8192*1024
    const size_t needed = ((size_t)8192 * 1024 + (size_t)3072 * 1024 + (size_t)1024 * 1024 +
                           (size_t)8192 * 2048 + (size_t)64 * 64 * 2048 + (size_t)8192 * 1024) * 2;
    if (ws_size < needed) return;

    pack_bf16_k<<<8192, 256, 0, stream>>>(x, xb, 8192 * 1024 / 4);
    transpose2_k<<<dim3(128, 32), dim3(32, 8), 0, stream>>>(w_attn, wTa, w_proj, wTp);
    gemm256<1><<<384, 512, 0, stream>>>(xb, wTa, b_attn, nullptr, qkb, vtb, 3072, 1024);
    attn_fwd<<<dim3(8, 64), 256, 0, stream>>>(qkb, vtb, aob);
    gemm256<0><<<128, 512, 0, stream>>>(aob, wTp, b_proj, out, nullptr, nullptr, 1024, 1024);
}